// Round 1
// baseline (468.489 us; speedup 1.0000x reference)
//
#include <hip/hip_runtime.h>
#include <math.h>

#define NN 20000
#define KK 16
#define DD 256
#define VV 64

__device__ __forceinline__ float4 ld4(const float* p) { return *reinterpret_cast<const float4*>(p); }
__device__ __forceinline__ void st4(float* p, float4 v) { *reinterpret_cast<float4*>(p) = v; }

// EW[v][d] = sum_j edge_emb[v][j] * W[256+j][d]   (edge table folded through W_bot)
__global__ __launch_bounds__(256) void ewk(const float* __restrict__ emb,
                                           const float* __restrict__ W,
                                           float* __restrict__ EW) {
    int v = blockIdx.x, d = threadIdx.x;
    float acc = 0.f;
    for (int j = 0; j < 256; ++j)
        acc += emb[v * DD + j] * W[(size_t)(256 + j) * DD + d];
    EW[v * DD + d] = acc;
}

// Layer-1 aggregation: S1[n] = sum_{dir,k} m * x[idx];  pre[n] = x[n] + 2*b1 + sum m*EW1[edge]
// One wave (64 lanes) per node, float4 per lane over D=256.
__global__ __launch_bounds__(256) void agg1(
    const float* __restrict__ x, const int* __restrict__ ii, const int* __restrict__ ie,
    const float* __restrict__ im, const int* __restrict__ oi, const int* __restrict__ oe,
    const float* __restrict__ om, const float* __restrict__ EW, const float* __restrict__ b,
    float* __restrict__ S, float* __restrict__ pre) {
    int w = threadIdx.x >> 6, lane = threadIdx.x & 63;
    int n = blockIdx.x * 4 + w;
    __shared__ int sidx[4][32];
    __shared__ int sedg[4][32];
    __shared__ float smsk[4][32];
    if (lane < 16) {
        sidx[w][lane]      = ii[n * KK + lane];
        sidx[w][lane + 16] = oi[n * KK + lane];
        sedg[w][lane]      = ie[n * KK + lane];
        sedg[w][lane + 16] = oe[n * KK + lane];
        smsk[w][lane]      = im[n * KK + lane];
        smsk[w][lane + 16] = om[n * KK + lane];
    }
    __syncthreads();
    int c = lane * 4;
    float4 bb = ld4(b + c);
    float4 p = ld4(x + (size_t)n * DD + c);
    p.x += 2.f * bb.x; p.y += 2.f * bb.y; p.z += 2.f * bb.z; p.w += 2.f * bb.w;
    float4 s = make_float4(0.f, 0.f, 0.f, 0.f);
    #pragma unroll 4
    for (int j = 0; j < 32; ++j) {
        int idx = sidx[w][j];
        float m = smsk[w][j];
        int e = sedg[w][j];
        float4 xr = ld4(x + (size_t)idx * DD + c);
        float4 er = ld4(EW + (size_t)e * DD + c);
        s.x += m * xr.x; s.y += m * xr.y; s.z += m * xr.z; s.w += m * xr.w;
        p.x += m * er.x; p.y += m * er.y; p.z += m * er.z; p.w += m * er.w;
    }
    st4(S + (size_t)n * DD + c, s);
    st4(pre + (size_t)n * DD + c, p);
}

// Shared aggregation for gc2/gc3: S[n] = sum_{dir,k} m * hidden[idx]
__global__ __launch_bounds__(256) void agg2(
    const float* __restrict__ x, const int* __restrict__ ii, const float* __restrict__ im,
    const int* __restrict__ oi, const float* __restrict__ om, float* __restrict__ S) {
    int w = threadIdx.x >> 6, lane = threadIdx.x & 63;
    int n = blockIdx.x * 4 + w;
    __shared__ int sidx[4][32];
    __shared__ float smsk[4][32];
    if (lane < 16) {
        sidx[w][lane]      = ii[n * KK + lane];
        sidx[w][lane + 16] = oi[n * KK + lane];
        smsk[w][lane]      = im[n * KK + lane];
        smsk[w][lane + 16] = om[n * KK + lane];
    }
    __syncthreads();
    int c = lane * 4;
    float4 s = make_float4(0.f, 0.f, 0.f, 0.f);
    #pragma unroll 4
    for (int j = 0; j < 32; ++j) {
        int idx = sidx[w][j];
        float m = smsk[w][j];
        float4 xr = ld4(x + (size_t)idx * DD + c);
        s.x += m * xr.x; s.y += m * xr.y; s.z += m * xr.z; s.w += m * xr.w;
    }
    st4(S + (size_t)n * DD + c, s);
}

// out[n] += S[n] @ W_top   (32-node tile, thread = 4 cols x 8 nodes register block)
__global__ __launch_bounds__(256) void m1(const float* __restrict__ S,
                                          const float* __restrict__ W,
                                          float* __restrict__ out) {
    __shared__ float st[256 * 33];  // st[k*33+i] = S[(n0+i)*256+k], +1 pad: conflict-free
    int n0 = blockIdx.x * 32;
    for (int i = 0; i < 32; ++i)
        st[threadIdx.x * 33 + i] = S[(size_t)(n0 + i) * DD + threadIdx.x];
    __syncthreads();
    int tx = threadIdx.x & 63, ty = threadIdx.x >> 6;
    int c = tx * 4, nb = ty * 8;
    float4 acc[8];
    #pragma unroll
    for (int j = 0; j < 8; ++j) acc[j] = make_float4(0.f, 0.f, 0.f, 0.f);
    for (int k = 0; k < 256; ++k) {
        float4 w = ld4(W + (size_t)k * DD + c);
        const float* sp = &st[k * 33 + nb];
        #pragma unroll
        for (int j = 0; j < 8; ++j) {
            float s = sp[j];
            acc[j].x += s * w.x; acc[j].y += s * w.y; acc[j].z += s * w.z; acc[j].w += s * w.w;
        }
    }
    #pragma unroll
    for (int j = 0; j < 8; ++j) {
        size_t o = (size_t)(n0 + nb + j) * DD + c;
        float4 v = ld4(out + o);
        v.x += acc[j].x; v.y += acc[j].y; v.z += acc[j].z; v.w += acc[j].w;
        st4(out + o, v);
    }
}

// Fused gc2+gc3 matmuls + edge terms + tanh + separable KLD partial reduction.
// pass0: mu = hidden + 2*b2 + E2 + S@W2top  -> kacc += 1 - tanh(mu)^2
// pass1: lv = hidden + 2*b3 + E3 + S@W3top  -> kacc += 2*tanh(lv) - exp(2*tanh(lv))
__global__ __launch_bounds__(256) void m2(
    const float* __restrict__ hidden, const float* __restrict__ S,
    const float* __restrict__ W2, const float* __restrict__ b2, const float* __restrict__ EW2,
    const float* __restrict__ W3, const float* __restrict__ b3, const float* __restrict__ EW3,
    const int* __restrict__ ie, const int* __restrict__ oe,
    const float* __restrict__ im, const float* __restrict__ om,
    float* __restrict__ partials) {
    __shared__ float st[256 * 33];
    __shared__ int sedg[32][32];
    __shared__ float smsk[32][32];
    __shared__ float red[256];
    int n0 = blockIdx.x * 32;
    for (int i = 0; i < 32; ++i)
        st[threadIdx.x * 33 + i] = S[(size_t)(n0 + i) * DD + threadIdx.x];
    for (int q = threadIdx.x; q < 1024; q += 256) {
        int i = q >> 5, j = q & 31;
        int gi = (n0 + i) * KK;
        sedg[i][j] = (j < 16) ? ie[gi + j] : oe[gi + j - 16];
        smsk[i][j] = (j < 16) ? im[gi + j] : om[gi + j - 16];
    }
    __syncthreads();
    int tx = threadIdx.x & 63, ty = threadIdx.x >> 6;
    int c = tx * 4, nb = ty * 8;
    float kacc = 0.f;
    for (int pass = 0; pass < 2; ++pass) {
        const float* W  = pass ? W3 : W2;
        const float* bp = pass ? b3 : b2;
        const float* EW = pass ? EW3 : EW2;
        float4 acc[8];
        #pragma unroll
        for (int j = 0; j < 8; ++j) acc[j] = make_float4(0.f, 0.f, 0.f, 0.f);
        for (int k = 0; k < 256; ++k) {
            float4 w = ld4(W + (size_t)k * DD + c);
            const float* sp = &st[k * 33 + nb];
            #pragma unroll
            for (int j = 0; j < 8; ++j) {
                float s = sp[j];
                acc[j].x += s * w.x; acc[j].y += s * w.y; acc[j].z += s * w.z; acc[j].w += s * w.w;
            }
        }
        float4 bb = ld4(bp + c);
        for (int j = 0; j < 8; ++j) {
            int i = nb + j;
            float4 e = make_float4(0.f, 0.f, 0.f, 0.f);
            #pragma unroll 4
            for (int q = 0; q < 32; ++q) {
                int ed = sedg[i][q];
                float m = smsk[i][q];
                float4 v = ld4(EW + (size_t)ed * DD + c);
                e.x += m * v.x; e.y += m * v.y; e.z += m * v.z; e.w += m * v.w;
            }
            float4 h = ld4(hidden + (size_t)(n0 + i) * DD + c);
            float mv[4];
            mv[0] = h.x + 2.f * bb.x + e.x + acc[j].x;
            mv[1] = h.y + 2.f * bb.y + e.y + acc[j].y;
            mv[2] = h.z + 2.f * bb.z + e.z + acc[j].z;
            mv[3] = h.w + 2.f * bb.w + e.w + acc[j].w;
            if (pass == 0) {
                #pragma unroll
                for (int z = 0; z < 4; ++z) { float t = tanhf(mv[z]); kacc += 1.f - t * t; }
            } else {
                #pragma unroll
                for (int z = 0; z < 4; ++z) { float t = tanhf(mv[z]); kacc += 2.f * t - expf(2.f * t); }
            }
        }
    }
    red[threadIdx.x] = kacc;
    __syncthreads();
    for (int sft = 128; sft > 0; sft >>= 1) {
        if (threadIdx.x < sft) red[threadIdx.x] += red[threadIdx.x + sft];
        __syncthreads();
    }
    if (threadIdx.x == 0) partials[blockIdx.x] = red[0];
}

__global__ __launch_bounds__(256) void kred(const float* __restrict__ partials, int np,
                                            float* __restrict__ out) {
    __shared__ double red[256];
    double l = 0.0;
    for (int i = threadIdx.x; i < np; i += 256) l += (double)partials[i];
    red[threadIdx.x] = l;
    __syncthreads();
    for (int s = 128; s > 0; s >>= 1) {
        if (threadIdx.x < s) red[threadIdx.x] += red[threadIdx.x + s];
        __syncthreads();
    }
    if (threadIdx.x == 0)
        out[0] = (float)(red[0] * (-0.5 / ((double)NN * (double)NN)));
}

extern "C" void kernel_launch(void* const* d_in, const int* in_sizes, int n_in,
                              void* d_out, int out_size, void* d_ws, size_t ws_size,
                              hipStream_t stream) {
    const float* x  = (const float*)d_in[0];
    const int*   ii = (const int*)d_in[1];
    const int*   ie = (const int*)d_in[2];
    const float* im = (const float*)d_in[3];
    const int*   oi = (const int*)d_in[4];
    const int*   oe = (const int*)d_in[5];
    const float* om = (const float*)d_in[6];
    const float* e1 = (const float*)d_in[7];
    const float* W1 = (const float*)d_in[8];
    const float* b1 = (const float*)d_in[9];
    const float* e2 = (const float*)d_in[10];
    const float* W2 = (const float*)d_in[11];
    const float* b2 = (const float*)d_in[12];
    const float* e3 = (const float*)d_in[13];
    const float* W3 = (const float*)d_in[14];
    const float* b3 = (const float*)d_in[15];
    float* out = (float*)d_out;  // hidden [N*256] then kld scalar

    float* S     = (float*)d_ws;             // N*256 f32
    float* EW1   = S + (size_t)NN * DD;      // 64*256
    float* EW2   = EW1 + VV * DD;
    float* EW3   = EW2 + VV * DD;
    float* parts = EW3 + VV * DD;            // 625

    ewk<<<VV, 256, 0, stream>>>(e1, W1, EW1);
    ewk<<<VV, 256, 0, stream>>>(e2, W2, EW2);
    ewk<<<VV, 256, 0, stream>>>(e3, W3, EW3);
    agg1<<<NN / 4, 256, 0, stream>>>(x, ii, ie, im, oi, oe, om, EW1, b1, S, out);
    m1<<<NN / 32, 256, 0, stream>>>(S, W1, out);
    agg2<<<NN / 4, 256, 0, stream>>>(out, ii, im, oi, om, S);
    m2<<<NN / 32, 256, 0, stream>>>(out, S, W2, b2, EW2, W3, b3, EW3, ie, oe, im, om, parts);
    kred<<<1, 256, 0, stream>>>(parts, NN / 32, out + (size_t)NN * DD);
}

// Round 2
// 264.417 us; speedup vs baseline: 1.7718x; 1.7718x over previous
//
#include <hip/hip_runtime.h>
#include <math.h>

#define NN 20000
#define KK 16
#define DD 256
#define VV 64
#define NT1 16
#define NT23 32

typedef __attribute__((ext_vector_type(8))) __bf16 bf16x8;
typedef __attribute__((ext_vector_type(4))) float floatx4;

__device__ __forceinline__ float4 ld4(const float* p) { return *reinterpret_cast<const float4*>(p); }

__device__ __forceinline__ unsigned short f2bf(float f) {
    union { float f; unsigned u; } v; v.f = f;
    unsigned r = v.u + 0x7FFFu + ((v.u >> 16) & 1u);
    return (unsigned short)(r >> 16);
}
__device__ __forceinline__ float bf2f(unsigned short u) {
    union { unsigned u; float f; } v; v.u = ((unsigned)u) << 16;
    return v.f;
}

// EW[layer][v][d] = sum_j emb_l[v][j] * W_l[256+j][d]  (edge table folded through W_bot)
__global__ __launch_bounds__(256) void ewk3(const float* __restrict__ e1, const float* __restrict__ W1,
                                            const float* __restrict__ e2, const float* __restrict__ W2,
                                            const float* __restrict__ e3, const float* __restrict__ W3,
                                            float* __restrict__ EW) {
    int layer = blockIdx.y;
    const float* emb = layer == 0 ? e1 : (layer == 1 ? e2 : e3);
    const float* W   = layer == 0 ? W1 : (layer == 1 ? W2 : W3);
    int v = blockIdx.x, d = threadIdx.x;
    float acc = 0.f;
    for (int j = 0; j < 256; ++j)
        acc += emb[v * DD + j] * W[(size_t)(256 + j) * DD + d];
    EW[(size_t)layer * VV * DD + v * DD + d] = acc;
}

// Pack B = [W_top(256 rows); EW(64 rows)] (K=320 x Ncols) into MFMA B-fragment layout:
// U[((kt*NT + nt)*64 + lane)*8 + j] = B[kt*32 + (lane>>4)*8 + j][nt*16 + (lane&15)]  as bf16
__global__ __launch_bounds__(256) void packU(const float* __restrict__ Wa, const float* __restrict__ EWa,
                                             const float* __restrict__ Wb, const float* __restrict__ EWb,
                                             int NT, unsigned short* __restrict__ U) {
    int g = blockIdx.x * 256 + threadIdx.x;  // (kt*NT + nt)*64 + lane
    int lane = g & 63, ntk = g >> 6;
    int nt = ntk % NT, kt = ntk / NT;
    if (kt >= 10) return;
    int n = nt * 16 + (lane & 15);
    int kbase = kt * 32 + (lane >> 4) * 8;
    const float* W = Wa; const float* EW = EWa;
    if (n >= 256) { W = Wb; EW = EWb; n -= 256; }
    unsigned short o8[8];
    #pragma unroll
    for (int j = 0; j < 8; ++j) {
        int k = kbase + j;
        float v = (k < 256) ? W[(size_t)k * DD + n] : EW[(size_t)(k - 256) * DD + n];
        o8[j] = f2bf(v);
    }
    *reinterpret_cast<uint4*>(&U[(size_t)g * 8]) = *reinterpret_cast<uint4*>(o8);
}

// Masked edge histogram, shared by all 3 layers: H[n][v] = sum m * [e == v]
// One wave per node; lane = vocab slot. Written into Sb cols [256, 320).
__global__ __launch_bounds__(256) void hist(const int* __restrict__ ie, const float* __restrict__ im,
                                            const int* __restrict__ oe, const float* __restrict__ om,
                                            unsigned short* __restrict__ Sb) {
    int w = threadIdx.x >> 6, lane = threadIdx.x & 63;
    int n = blockIdx.x * 4 + w;
    int e = 0; float m = 0.f;
    if (lane < 16)      { e = ie[n * KK + lane];      m = im[n * KK + lane]; }
    else if (lane < 32) { e = oe[n * KK + lane - 16]; m = om[n * KK + lane - 16]; }
    float h = 0.f;
    #pragma unroll
    for (int j = 0; j < 32; ++j) {
        int ev = __shfl(e, j);
        float mv = __shfl(m, j);
        if (ev == lane) h += mv;
    }
    Sb[(size_t)n * 320 + 256 + lane] = f2bf(h);
}

__global__ __launch_bounds__(256) void xcast(const float* __restrict__ x, unsigned short* __restrict__ xh) {
    int i = blockIdx.x * 256 + threadIdx.x;
    float4 v = ld4(x + (size_t)i * 4);
    ushort4 o; o.x = f2bf(v.x); o.y = f2bf(v.y); o.z = f2bf(v.z); o.w = f2bf(v.w);
    *reinterpret_cast<ushort4*>(xh + (size_t)i * 4) = o;
}

// Gather-aggregate from f32 rows: Sb[n][0:256] = bf16( sum m * src[idx] )
__global__ __launch_bounds__(256) void aggf(const float* __restrict__ src, const int* __restrict__ ii,
                                            const float* __restrict__ im, const int* __restrict__ oi,
                                            const float* __restrict__ om, unsigned short* __restrict__ Sb) {
    int w = threadIdx.x >> 6, lane = threadIdx.x & 63;
    int n = blockIdx.x * 4 + w;
    __shared__ int sidx[4][32];
    __shared__ float smsk[4][32];
    if (lane < 16) {
        sidx[w][lane] = ii[n * KK + lane]; sidx[w][lane + 16] = oi[n * KK + lane];
        smsk[w][lane] = im[n * KK + lane]; smsk[w][lane + 16] = om[n * KK + lane];
    }
    __syncthreads();
    int c = lane * 4;
    float4 s = make_float4(0.f, 0.f, 0.f, 0.f);
    #pragma unroll 4
    for (int j = 0; j < 32; ++j) {
        float4 xr = ld4(src + (size_t)sidx[w][j] * DD + c);
        float m = smsk[w][j];
        s.x += m * xr.x; s.y += m * xr.y; s.z += m * xr.z; s.w += m * xr.w;
    }
    ushort4 o; o.x = f2bf(s.x); o.y = f2bf(s.y); o.z = f2bf(s.z); o.w = f2bf(s.w);
    *reinterpret_cast<ushort4*>(&Sb[(size_t)n * 320 + c]) = o;
}

// Same, gathering from bf16 rows (half the L2/L3 traffic)
__global__ __launch_bounds__(256) void aggh(const unsigned short* __restrict__ src, const int* __restrict__ ii,
                                            const float* __restrict__ im, const int* __restrict__ oi,
                                            const float* __restrict__ om, unsigned short* __restrict__ Sb) {
    int w = threadIdx.x >> 6, lane = threadIdx.x & 63;
    int n = blockIdx.x * 4 + w;
    __shared__ int sidx[4][32];
    __shared__ float smsk[4][32];
    if (lane < 16) {
        sidx[w][lane] = ii[n * KK + lane]; sidx[w][lane + 16] = oi[n * KK + lane];
        smsk[w][lane] = im[n * KK + lane]; smsk[w][lane + 16] = om[n * KK + lane];
    }
    __syncthreads();
    int c = lane * 4;
    float4 s = make_float4(0.f, 0.f, 0.f, 0.f);
    #pragma unroll 4
    for (int j = 0; j < 32; ++j) {
        ushort4 u = *reinterpret_cast<const ushort4*>(src + (size_t)sidx[w][j] * DD + c);
        float m = smsk[w][j];
        s.x += m * bf2f(u.x); s.y += m * bf2f(u.y); s.z += m * bf2f(u.z); s.w += m * bf2f(u.w);
    }
    ushort4 o; o.x = f2bf(s.x); o.y = f2bf(s.y); o.z = f2bf(s.z); o.w = f2bf(s.w);
    *reinterpret_cast<ushort4*>(&Sb[(size_t)n * 320 + c]) = o;
}

// hidden = x + 2*b1 + [S1|H] @ U1   (MFMA bf16, fp32 acc). Optionally also writes bf16 copy.
// Block: 32 rows x 256 cols; 4 waves each 32 rows x 64 cols (2 Mtiles x 4 Ntiles).
__global__ __launch_bounds__(256) void mm1(const unsigned short* __restrict__ Sb, const unsigned short* __restrict__ U,
                                           const float* __restrict__ x, const float* __restrict__ b,
                                           float* __restrict__ out, unsigned short* __restrict__ hb) {
    __shared__ unsigned short sA[32 * 336];
    int n0 = blockIdx.x * 32;
    for (int c = threadIdx.x; c < 1280; c += 256) {
        int row = c / 40, k8 = c % 40;
        *reinterpret_cast<uint4*>(&sA[row * 336 + k8 * 8]) =
            *reinterpret_cast<const uint4*>(&Sb[(size_t)(n0 + row) * 320 + k8 * 8]);
    }
    __syncthreads();
    int lane = threadIdx.x & 63, w = threadIdx.x >> 6;
    int lr = lane & 15, quad = lane >> 4;
    floatx4 z = {0.f, 0.f, 0.f, 0.f};
    floatx4 acc[2][4] = {{z, z, z, z}, {z, z, z, z}};
    for (int kt = 0; kt < 10; ++kt) {
        int kof = kt * 32 + quad * 8;
        bf16x8 a0 = *reinterpret_cast<const bf16x8*>(&sA[lr * 336 + kof]);
        bf16x8 a1 = *reinterpret_cast<const bf16x8*>(&sA[(lr + 16) * 336 + kof]);
        #pragma unroll
        for (int t = 0; t < 4; ++t) {
            int nt = w * 4 + t;
            bf16x8 bf = *reinterpret_cast<const bf16x8*>(&U[(size_t)((kt * NT1 + nt) * 64 + lane) * 8]);
            acc[0][t] = __builtin_amdgcn_mfma_f32_16x16x32_bf16(a0, bf, acc[0][t], 0, 0, 0);
            acc[1][t] = __builtin_amdgcn_mfma_f32_16x16x32_bf16(a1, bf, acc[1][t], 0, 0, 0);
        }
    }
    #pragma unroll
    for (int mt = 0; mt < 2; ++mt) {
        #pragma unroll
        for (int t = 0; t < 4; ++t) {
            int col = (w * 4 + t) * 16 + lr;
            float bb = 2.f * b[col];
            #pragma unroll
            for (int r = 0; r < 4; ++r) {
                int row = n0 + mt * 16 + quad * 4 + r;
                size_t o = (size_t)row * DD + col;
                float v = x[o] + bb + acc[mt][t][r];
                out[o] = v;
                if (hb) hb[o] = f2bf(v);
            }
        }
    }
}

// Fused gc2+gc3: acc = [S2|H] @ U23 (512 cols: mu | logvar); v = hidden + 2*b + acc;
// tanh + separable KLD partial per block. blockIdx.y: 0 = mu pass, 1 = logvar pass.
__global__ __launch_bounds__(256) void mm23(const unsigned short* __restrict__ Sb, const unsigned short* __restrict__ U,
                                            const float* __restrict__ hidden, const float* __restrict__ b2,
                                            const float* __restrict__ b3, float* __restrict__ partials) {
    __shared__ unsigned short sA[32 * 336];
    __shared__ float red[256];
    int n0 = blockIdx.x * 32;
    int pass = blockIdx.y;
    for (int c = threadIdx.x; c < 1280; c += 256) {
        int row = c / 40, k8 = c % 40;
        *reinterpret_cast<uint4*>(&sA[row * 336 + k8 * 8]) =
            *reinterpret_cast<const uint4*>(&Sb[(size_t)(n0 + row) * 320 + k8 * 8]);
    }
    __syncthreads();
    int lane = threadIdx.x & 63, w = threadIdx.x >> 6;
    int lr = lane & 15, quad = lane >> 4;
    floatx4 z = {0.f, 0.f, 0.f, 0.f};
    floatx4 acc[2][4] = {{z, z, z, z}, {z, z, z, z}};
    for (int kt = 0; kt < 10; ++kt) {
        int kof = kt * 32 + quad * 8;
        bf16x8 a0 = *reinterpret_cast<const bf16x8*>(&sA[lr * 336 + kof]);
        bf16x8 a1 = *reinterpret_cast<const bf16x8*>(&sA[(lr + 16) * 336 + kof]);
        #pragma unroll
        for (int t = 0; t < 4; ++t) {
            int nt = pass * 16 + w * 4 + t;
            bf16x8 bf = *reinterpret_cast<const bf16x8*>(&U[(size_t)((kt * NT23 + nt) * 64 + lane) * 8]);
            acc[0][t] = __builtin_amdgcn_mfma_f32_16x16x32_bf16(a0, bf, acc[0][t], 0, 0, 0);
            acc[1][t] = __builtin_amdgcn_mfma_f32_16x16x32_bf16(a1, bf, acc[1][t], 0, 0, 0);
        }
    }
    const float* b = pass ? b3 : b2;
    float kacc = 0.f;
    #pragma unroll
    for (int mt = 0; mt < 2; ++mt) {
        #pragma unroll
        for (int t = 0; t < 4; ++t) {
            int col = (w * 4 + t) * 16 + lr;
            float bb = 2.f * b[col];
            #pragma unroll
            for (int r = 0; r < 4; ++r) {
                int row = n0 + mt * 16 + quad * 4 + r;
                float v = hidden[(size_t)row * DD + col] + bb + acc[mt][t][r];
                float th = tanhf(v);
                kacc += pass == 0 ? (1.f - th * th) : (2.f * th - expf(2.f * th));
            }
        }
    }
    red[threadIdx.x] = kacc;
    __syncthreads();
    for (int s = 128; s > 0; s >>= 1) {
        if (threadIdx.x < s) red[threadIdx.x] += red[threadIdx.x + s];
        __syncthreads();
    }
    if (threadIdx.x == 0) partials[pass * 625 + blockIdx.x] = red[0];
}

__global__ __launch_bounds__(256) void kred(const float* __restrict__ partials, int np,
                                            float* __restrict__ out) {
    __shared__ double red[256];
    double l = 0.0;
    for (int i = threadIdx.x; i < np; i += 256) l += (double)partials[i];
    red[threadIdx.x] = l;
    __syncthreads();
    for (int s = 128; s > 0; s >>= 1) {
        if (threadIdx.x < s) red[threadIdx.x] += red[threadIdx.x + s];
        __syncthreads();
    }
    if (threadIdx.x == 0)
        out[0] = (float)(red[0] * (-0.5 / ((double)NN * (double)NN)));
}

extern "C" void kernel_launch(void* const* d_in, const int* in_sizes, int n_in,
                              void* d_out, int out_size, void* d_ws, size_t ws_size,
                              hipStream_t stream) {
    const float* x  = (const float*)d_in[0];
    const int*   ii = (const int*)d_in[1];
    const int*   ie = (const int*)d_in[2];
    const float* im = (const float*)d_in[3];
    const int*   oi = (const int*)d_in[4];
    const int*   oe = (const int*)d_in[5];
    const float* om = (const float*)d_in[6];
    const float* e1 = (const float*)d_in[7];
    const float* W1 = (const float*)d_in[8];
    const float* b1 = (const float*)d_in[9];
    const float* e2 = (const float*)d_in[10];
    const float* W2 = (const float*)d_in[11];
    const float* b2 = (const float*)d_in[12];
    const float* e3 = (const float*)d_in[13];
    const float* W3 = (const float*)d_in[14];
    const float* b3 = (const float*)d_in[15];
    float* out = (float*)d_out;

    char* ws = (char*)d_ws;
    float*          EW    = (float*)(ws);                    // 3*64*256 f32       (196608 B)
    unsigned short* U1    = (unsigned short*)(ws + 196608);  // 10*16*64*8 bf16    (163840 B)
    unsigned short* U23   = (unsigned short*)(ws + 360448);  // 10*32*64*8 bf16    (327680 B)
    float*          parts = (float*)(ws + 688128);           // 1250 f32
    unsigned short* Sb    = (unsigned short*)(ws + 693248);  // 20000*320 bf16     (12.8 MB)
    unsigned short* xh    = (unsigned short*)(ws + 13493248);// 20000*256 bf16     (10.24 MB, optional; aliased for hidden-bf16)
    int useBf = ws_size >= (size_t)23733248;

    ewk3 <<<dim3(VV, 3), 256, 0, stream>>>(e1, W1, e2, W2, e3, W3, EW);
    packU<<<40, 256, 0, stream>>>(W1, EW, W1, EW, NT1, U1);
    packU<<<80, 256, 0, stream>>>(W2, EW + VV * DD, W3, EW + 2 * VV * DD, NT23, U23);
    hist <<<NN / 4, 256, 0, stream>>>(ie, im, oe, om, Sb);
    if (useBf) {
        xcast<<<NN * DD / 4 / 256, 256, 0, stream>>>(x, xh);
        aggh<<<NN / 4, 256, 0, stream>>>(xh, ii, im, oi, om, Sb);
    } else {
        aggf<<<NN / 4, 256, 0, stream>>>(x, ii, im, oi, om, Sb);
    }
    mm1<<<NN / 32, 256, 0, stream>>>(Sb, U1, x, b1, out, useBf ? xh : (unsigned short*)nullptr);
    if (useBf) aggh<<<NN / 4, 256, 0, stream>>>(xh, ii, im, oi, om, Sb);
    else       aggf<<<NN / 4, 256, 0, stream>>>(out, ii, im, oi, om, Sb);
    mm23<<<dim3(NN / 32, 2), 256, 0, stream>>>(Sb, U23, out, b2, b3, parts);
    kred<<<1, 256, 0, stream>>>(parts, 1250, out + (size_t)NN * DD);
}

// Round 3
// 252.155 us; speedup vs baseline: 1.8579x; 1.0486x over previous
//
#include <hip/hip_runtime.h>
#include <math.h>

#define NN 20000
#define KK 16
#define DD 256
#define VV 64
#define NT1 16
#define NT23 32

typedef __attribute__((ext_vector_type(8))) __bf16 bf16x8;
typedef __attribute__((ext_vector_type(4))) float floatx4;
typedef __attribute__((ext_vector_type(8))) unsigned short ushort8;

__device__ __forceinline__ float4 ld4(const float* p) { return *reinterpret_cast<const float4*>(p); }

__device__ __forceinline__ unsigned short f2bf(float f) {
    union { float f; unsigned u; } v; v.f = f;
    unsigned r = v.u + 0x7FFFu + ((v.u >> 16) & 1u);
    return (unsigned short)(r >> 16);
}
__device__ __forceinline__ float bf2f(unsigned short u) {
    union { unsigned u; float f; } v; v.u = ((unsigned)u) << 16;
    return v.f;
}

// EW[layer][v][d] = sum_j emb_l[v][j] * W_l[256+j][d]
__global__ __launch_bounds__(256) void ewk3(const float* __restrict__ e1, const float* __restrict__ W1,
                                            const float* __restrict__ e2, const float* __restrict__ W2,
                                            const float* __restrict__ e3, const float* __restrict__ W3,
                                            float* __restrict__ EW) {
    int layer = blockIdx.y;
    const float* emb = layer == 0 ? e1 : (layer == 1 ? e2 : e3);
    const float* W   = layer == 0 ? W1 : (layer == 1 ? W2 : W3);
    int v = blockIdx.x, d = threadIdx.x;
    float acc = 0.f;
    #pragma unroll 8
    for (int j = 0; j < 256; ++j)
        acc += emb[v * DD + j] * W[(size_t)(256 + j) * DD + d];
    EW[(size_t)layer * VV * DD + v * DD + d] = acc;
}

// Pack B = [W_top(256); EW(64)] (K=320 x Ncols) into MFMA B-fragment layout.
__global__ __launch_bounds__(256) void packU(const float* __restrict__ Wa, const float* __restrict__ EWa,
                                             const float* __restrict__ Wb, const float* __restrict__ EWb,
                                             int NT, unsigned short* __restrict__ U) {
    int g = blockIdx.x * 256 + threadIdx.x;  // (kt*NT + nt)*64 + lane
    int lane = g & 63, ntk = g >> 6;
    int nt = ntk % NT, kt = ntk / NT;
    if (kt >= 10) return;
    int n = nt * 16 + (lane & 15);
    int kbase = kt * 32 + (lane >> 4) * 8;
    const float* W = Wa; const float* EW = EWa;
    if (n >= 256) { W = Wb; EW = EWb; n -= 256; }
    unsigned short o8[8];
    #pragma unroll
    for (int j = 0; j < 8; ++j) {
        int k = kbase + j;
        float v = (k < 256) ? W[(size_t)k * DD + n] : EW[(size_t)(k - 256) * DD + n];
        o8[j] = f2bf(v);
    }
    *reinterpret_cast<uint4*>(&U[(size_t)g * 8]) = *reinterpret_cast<uint4*>(o8);
}

// Shared masked edge histogram -> Sb cols [256,320); plus x -> bf16 cast (xh) if present.
__global__ __launch_bounds__(256) void prep(const int* __restrict__ ie, const float* __restrict__ im,
                                            const int* __restrict__ oe, const float* __restrict__ om,
                                            const float* __restrict__ x,
                                            unsigned short* __restrict__ Sb, unsigned short* __restrict__ xh) {
    int w = threadIdx.x >> 6, lane = threadIdx.x & 63;
    int n = blockIdx.x * 4 + w;
    int e = 0; float m = 0.f;
    if (lane < 16)      { e = ie[n * KK + lane];      m = im[n * KK + lane]; }
    else if (lane < 32) { e = oe[n * KK + lane - 16]; m = om[n * KK + lane - 16]; }
    float h = 0.f;
    #pragma unroll
    for (int j = 0; j < 32; ++j) {
        int ev = __shfl(e, j);
        float mv = __shfl(m, j);
        if (ev == lane) h += mv;
    }
    Sb[(size_t)n * 320 + 256 + lane] = f2bf(h);
    if (xh) {
        size_t base = (size_t)blockIdx.x * 1024 + threadIdx.x * 4;
        float4 v = ld4(x + base);
        ushort4 o; o.x = f2bf(v.x); o.y = f2bf(v.y); o.z = f2bf(v.z); o.w = f2bf(v.w);
        *reinterpret_cast<ushort4*>(xh + base) = o;
    }
}

// Half-wave bf16 gather-aggregate: lanes 0-31 even neighbors, 32-63 odd; 16B/lane loads.
__global__ __launch_bounds__(256) void aggh(const unsigned short* __restrict__ src, const int* __restrict__ ii,
                                            const float* __restrict__ im, const int* __restrict__ oi,
                                            const float* __restrict__ om, unsigned short* __restrict__ Sb) {
    int w = threadIdx.x >> 6, lane = threadIdx.x & 63;
    int n = blockIdx.x * 4 + w;
    __shared__ int sidx[4][32];
    __shared__ float smsk[4][32];
    if (lane < 16) {
        sidx[w][lane] = ii[n * KK + lane]; sidx[w][lane + 16] = oi[n * KK + lane];
        smsk[w][lane] = im[n * KK + lane]; smsk[w][lane + 16] = om[n * KK + lane];
    }
    __syncthreads();
    int half = lane >> 5, c = (lane & 31) * 8;
    float acc[8] = {0.f, 0.f, 0.f, 0.f, 0.f, 0.f, 0.f, 0.f};
    #pragma unroll
    for (int j = 0; j < 16; ++j) {
        int j2 = j * 2 + half;
        int idx = sidx[w][j2];
        float m = smsk[w][j2];
        ushort8 u = *reinterpret_cast<const ushort8*>(src + (size_t)idx * DD + c);
        #pragma unroll
        for (int z = 0; z < 8; ++z) acc[z] += m * bf2f(u[z]);
    }
    #pragma unroll
    for (int z = 0; z < 8; ++z) acc[z] += __shfl_xor(acc[z], 32);
    if (half == 0) {
        unsigned short o8[8];
        #pragma unroll
        for (int z = 0; z < 8; ++z) o8[z] = f2bf(acc[z]);
        *reinterpret_cast<uint4*>(&Sb[(size_t)n * 320 + c]) = *reinterpret_cast<uint4*>(o8);
    }
}

// f32-source fallback aggregate (full wave per row, float4/lane).
__global__ __launch_bounds__(256) void aggf(const float* __restrict__ src, const int* __restrict__ ii,
                                            const float* __restrict__ im, const int* __restrict__ oi,
                                            const float* __restrict__ om, unsigned short* __restrict__ Sb) {
    int w = threadIdx.x >> 6, lane = threadIdx.x & 63;
    int n = blockIdx.x * 4 + w;
    __shared__ int sidx[4][32];
    __shared__ float smsk[4][32];
    if (lane < 16) {
        sidx[w][lane] = ii[n * KK + lane]; sidx[w][lane + 16] = oi[n * KK + lane];
        smsk[w][lane] = im[n * KK + lane]; smsk[w][lane + 16] = om[n * KK + lane];
    }
    __syncthreads();
    int c = lane * 4;
    float4 s = make_float4(0.f, 0.f, 0.f, 0.f);
    #pragma unroll 4
    for (int j = 0; j < 32; ++j) {
        float4 xr = ld4(src + (size_t)sidx[w][j] * DD + c);
        float m = smsk[w][j];
        s.x += m * xr.x; s.y += m * xr.y; s.z += m * xr.z; s.w += m * xr.w;
    }
    ushort4 o; o.x = f2bf(s.x); o.y = f2bf(s.y); o.z = f2bf(s.z); o.w = f2bf(s.w);
    *reinterpret_cast<ushort4*>(&Sb[(size_t)n * 320 + c]) = o;
}

// hidden = x + 2*b1 + [S1|H] @ U1; 16-row tile, wave = 16 rows x 64 cols.
__global__ __launch_bounds__(256) void mm1(const unsigned short* __restrict__ Sb, const unsigned short* __restrict__ U,
                                           const float* __restrict__ x, const float* __restrict__ b,
                                           float* __restrict__ out, unsigned short* __restrict__ hb) {
    __shared__ unsigned short sA[16 * 336];
    int n0 = blockIdx.x * 16;
    for (int c = threadIdx.x; c < 640; c += 256) {
        int row = c / 40, k8 = c % 40;
        *reinterpret_cast<uint4*>(&sA[row * 336 + k8 * 8]) =
            *reinterpret_cast<const uint4*>(&Sb[(size_t)(n0 + row) * 320 + k8 * 8]);
    }
    __syncthreads();
    int lane = threadIdx.x & 63, w = threadIdx.x >> 6;
    int lr = lane & 15, quad = lane >> 4;
    float xp[4][4], bb[4];
    #pragma unroll
    for (int t = 0; t < 4; ++t) {
        int col = (w * 4 + t) * 16 + lr;
        bb[t] = 2.f * b[col];
        #pragma unroll
        for (int r = 0; r < 4; ++r)
            xp[t][r] = x[(size_t)(n0 + quad * 4 + r) * DD + col];
    }
    floatx4 z = {0.f, 0.f, 0.f, 0.f};
    floatx4 acc[4] = {z, z, z, z};
    for (int kt = 0; kt < 10; ++kt) {
        bf16x8 a = *reinterpret_cast<const bf16x8*>(&sA[lr * 336 + kt * 32 + quad * 8]);
        #pragma unroll
        for (int t = 0; t < 4; ++t) {
            bf16x8 bf = *reinterpret_cast<const bf16x8*>(&U[(size_t)((kt * NT1 + w * 4 + t) * 64 + lane) * 8]);
            acc[t] = __builtin_amdgcn_mfma_f32_16x16x32_bf16(a, bf, acc[t], 0, 0, 0);
        }
    }
    #pragma unroll
    for (int t = 0; t < 4; ++t) {
        int col = (w * 4 + t) * 16 + lr;
        #pragma unroll
        for (int r = 0; r < 4; ++r) {
            size_t o = (size_t)(n0 + quad * 4 + r) * DD + col;
            float v = xp[t][r] + bb[t] + acc[t][r];
            out[o] = v;
            if (hb) hb[o] = f2bf(v);
        }
    }
}

// Fused gc2/gc3 matmul + fast tanh + separable KLD. blockIdx.y: 0 = mu, 1 = logvar.
__global__ __launch_bounds__(256) void mm23(const unsigned short* __restrict__ Sb, const unsigned short* __restrict__ U,
                                            const unsigned short* __restrict__ hb, const float* __restrict__ hf,
                                            const float* __restrict__ b2, const float* __restrict__ b3,
                                            float* __restrict__ partials) {
    __shared__ unsigned short sA[16 * 336];
    __shared__ float red[4];
    int n0 = blockIdx.x * 16, pass = blockIdx.y;
    for (int c = threadIdx.x; c < 640; c += 256) {
        int row = c / 40, k8 = c % 40;
        *reinterpret_cast<uint4*>(&sA[row * 336 + k8 * 8]) =
            *reinterpret_cast<const uint4*>(&Sb[(size_t)(n0 + row) * 320 + k8 * 8]);
    }
    __syncthreads();
    int lane = threadIdx.x & 63, w = threadIdx.x >> 6;
    int lr = lane & 15, quad = lane >> 4;
    const float* b = pass ? b3 : b2;
    float hp[4][4], bb[4];
    #pragma unroll
    for (int t = 0; t < 4; ++t) {
        int col = (w * 4 + t) * 16 + lr;
        bb[t] = 2.f * b[col];
        #pragma unroll
        for (int r = 0; r < 4; ++r) {
            size_t o = (size_t)(n0 + quad * 4 + r) * DD + col;
            hp[t][r] = hb ? bf2f(hb[o]) : hf[o];
        }
    }
    floatx4 z = {0.f, 0.f, 0.f, 0.f};
    floatx4 acc[4] = {z, z, z, z};
    for (int kt = 0; kt < 10; ++kt) {
        bf16x8 a = *reinterpret_cast<const bf16x8*>(&sA[lr * 336 + kt * 32 + quad * 8]);
        #pragma unroll
        for (int t = 0; t < 4; ++t) {
            int nt = pass * 16 + w * 4 + t;
            bf16x8 bf = *reinterpret_cast<const bf16x8*>(&U[(size_t)((kt * NT23 + nt) * 64 + lane) * 8]);
            acc[t] = __builtin_amdgcn_mfma_f32_16x16x32_bf16(a, bf, acc[t], 0, 0, 0);
        }
    }
    float kacc = 0.f;
    #pragma unroll
    for (int t = 0; t < 4; ++t) {
        #pragma unroll
        for (int r = 0; r < 4; ++r) {
            float v = hp[t][r] + bb[t] + acc[t][r];
            float e = __expf(2.f * v);
            float tt = 1.f - 2.f * __builtin_amdgcn_rcpf(e + 1.f);  // tanh(v), exact at +/-inf
            kacc += (pass == 0) ? (1.f - tt * tt) : (2.f * tt - __expf(2.f * tt));
        }
    }
    #pragma unroll
    for (int off = 32; off > 0; off >>= 1) kacc += __shfl_xor(kacc, off);
    if (lane == 0) red[w] = kacc;
    __syncthreads();
    if (threadIdx.x == 0)
        partials[pass * 1250 + blockIdx.x] = red[0] + red[1] + red[2] + red[3];
}

__global__ __launch_bounds__(256) void kred(const float* __restrict__ partials, int np,
                                            float* __restrict__ out) {
    __shared__ double red[256];
    double l = 0.0;
    for (int i = threadIdx.x; i < np; i += 256) l += (double)partials[i];
    red[threadIdx.x] = l;
    __syncthreads();
    for (int s = 128; s > 0; s >>= 1) {
        if (threadIdx.x < s) red[threadIdx.x] += red[threadIdx.x + s];
        __syncthreads();
    }
    if (threadIdx.x == 0)
        out[0] = (float)(red[0] * (-0.5 / ((double)NN * (double)NN)));
}

extern "C" void kernel_launch(void* const* d_in, const int* in_sizes, int n_in,
                              void* d_out, int out_size, void* d_ws, size_t ws_size,
                              hipStream_t stream) {
    const float* x  = (const float*)d_in[0];
    const int*   ii = (const int*)d_in[1];
    const int*   ie = (const int*)d_in[2];
    const float* im = (const float*)d_in[3];
    const int*   oi = (const int*)d_in[4];
    const int*   oe = (const int*)d_in[5];
    const float* om = (const float*)d_in[6];
    const float* e1 = (const float*)d_in[7];
    const float* W1 = (const float*)d_in[8];
    const float* b1 = (const float*)d_in[9];
    const float* e2 = (const float*)d_in[10];
    const float* W2 = (const float*)d_in[11];
    const float* b2 = (const float*)d_in[12];
    const float* e3 = (const float*)d_in[13];
    const float* W3 = (const float*)d_in[14];
    const float* b3 = (const float*)d_in[15];
    float* out = (float*)d_out;

    char* ws = (char*)d_ws;
    float*          EW    = (float*)(ws);                     // 3*64*256 f32   (196608 B)
    unsigned short* U1    = (unsigned short*)(ws + 196608);   // 163840 B
    unsigned short* U23   = (unsigned short*)(ws + 360448);   // 327680 B
    float*          parts = (float*)(ws + 688128);            // 2500 f32 (10000 B)
    unsigned short* Sb    = (unsigned short*)(ws + 698128);   // 20000*320 bf16 (12.8 MB)
    unsigned short* xh    = (unsigned short*)(ws + 13498128); // 20000*256 bf16 (10.24 MB)
    int useBf = ws_size >= (size_t)23738128;

    ewk3 <<<dim3(VV, 3), 256, 0, stream>>>(e1, W1, e2, W2, e3, W3, EW);
    packU<<<40, 256, 0, stream>>>(W1, EW, W1, EW, NT1, U1);
    packU<<<80, 256, 0, stream>>>(W2, EW + VV * DD, W3, EW + 2 * VV * DD, NT23, U23);
    prep <<<NN / 4, 256, 0, stream>>>(ie, im, oe, om, x, Sb, useBf ? xh : (unsigned short*)nullptr);
    if (useBf) {
        aggh<<<NN / 4, 256, 0, stream>>>(xh, ii, im, oi, om, Sb);
        mm1 <<<NN / 16, 256, 0, stream>>>(Sb, U1, x, b1, out, xh);
        aggh<<<NN / 4, 256, 0, stream>>>(xh, ii, im, oi, om, Sb);
        mm23<<<dim3(NN / 16, 2), 256, 0, stream>>>(Sb, U23, xh, (const float*)nullptr, b2, b3, parts);
    } else {
        aggf<<<NN / 4, 256, 0, stream>>>(x, ii, im, oi, om, Sb);
        mm1 <<<NN / 16, 256, 0, stream>>>(Sb, U1, x, b1, out, (unsigned short*)nullptr);
        aggf<<<NN / 4, 256, 0, stream>>>(out, ii, im, oi, om, Sb);
        mm23<<<dim3(NN / 16, 2), 256, 0, stream>>>(Sb, U23, (const unsigned short*)nullptr, out, b2, b3, parts);
    }
    kred<<<1, 256, 0, stream>>>(parts, 2500, out + (size_t)NN * DD);
}

// Round 4
// 230.710 us; speedup vs baseline: 2.0306x; 1.0930x over previous
//
#include <hip/hip_runtime.h>
#include <math.h>

#define NN 20000
#define KK 16
#define DD 256
#define VV 64
#define NT1 16
#define NT23 32

typedef __attribute__((ext_vector_type(8))) __bf16 bf16x8;
typedef __attribute__((ext_vector_type(4))) float floatx4;
typedef __attribute__((ext_vector_type(2))) float floatx2;
typedef __attribute__((ext_vector_type(8))) unsigned short ushort8;

__device__ __forceinline__ float4 ld4(const float* p) { return *reinterpret_cast<const float4*>(p); }

__device__ __forceinline__ unsigned short f2bf(float f) {
    union { float f; unsigned u; } v; v.f = f;
    unsigned r = v.u + 0x7FFFu + ((v.u >> 16) & 1u);
    return (unsigned short)(r >> 16);
}
__device__ __forceinline__ float bf2f(unsigned short u) {
    union { unsigned u; float f; } v; v.u = ((unsigned)u) << 16;
    return v.f;
}
__device__ __forceinline__ unsigned char f2q(float f) {  // fp8 e4m3, RTNE
    return (unsigned char)(__builtin_amdgcn_cvt_pk_fp8_f32(f, 0.f, 0u, false) & 0xFFu);
}
__device__ __forceinline__ float q2f(unsigned char q) {
    floatx2 r = __builtin_amdgcn_cvt_pk_f32_fp8((unsigned)q, false);
    return r.x;
}

// EW[layer][v][d] = sum_j emb_l[v][j] * W_l[256+j][d]
__global__ __launch_bounds__(256) void ewk3(const float* __restrict__ e1, const float* __restrict__ W1,
                                            const float* __restrict__ e2, const float* __restrict__ W2,
                                            const float* __restrict__ e3, const float* __restrict__ W3,
                                            float* __restrict__ EW) {
    int layer = blockIdx.y;
    const float* emb = layer == 0 ? e1 : (layer == 1 ? e2 : e3);
    const float* W   = layer == 0 ? W1 : (layer == 1 ? W2 : W3);
    int v = blockIdx.x, d = threadIdx.x;
    float acc = 0.f;
    #pragma unroll 8
    for (int j = 0; j < 256; ++j)
        acc += emb[v * DD + j] * W[(size_t)(256 + j) * DD + d];
    EW[(size_t)layer * VV * DD + v * DD + d] = acc;
}

// Pack B = [W_top(256); EW(64)] (K=320) into MFMA B-fragment layout; U1 and U23 in one launch.
__global__ __launch_bounds__(256) void packU2(const float* __restrict__ W1, const float* __restrict__ EW1,
                                              const float* __restrict__ W2, const float* __restrict__ EW2,
                                              const float* __restrict__ W3, const float* __restrict__ EW3,
                                              unsigned short* __restrict__ U1, unsigned short* __restrict__ U23) {
    int blk = blockIdx.x;
    int NT; unsigned short* U; const float *Wa, *EWa, *Wb, *EWb; int g;
    if (blk < 40) { NT = NT1;  U = U1;  Wa = W1; EWa = EW1; Wb = W1; EWb = EW1; g = blk * 256 + threadIdx.x; }
    else          { NT = NT23; U = U23; Wa = W2; EWa = EW2; Wb = W3; EWb = EW3; g = (blk - 40) * 256 + threadIdx.x; }
    int lane = g & 63, ntk = g >> 6;
    int nt = ntk % NT, kt = ntk / NT;
    if (kt >= 10) return;
    int n = nt * 16 + (lane & 15);
    int kbase = kt * 32 + (lane >> 4) * 8;
    const float* W = Wa; const float* EW = EWa;
    if (n >= 256) { W = Wb; EW = EWb; n -= 256; }
    unsigned short o8[8];
    #pragma unroll
    for (int j = 0; j < 8; ++j) {
        int k = kbase + j;
        float v = (k < 256) ? W[(size_t)k * DD + n] : EW[(size_t)(k - 256) * DD + n];
        o8[j] = f2bf(v);
    }
    *reinterpret_cast<uint4*>(&U[(size_t)g * 8]) = *reinterpret_cast<uint4*>(o8);
}

// Shared masked edge histogram -> Sb cols [256,320); plus x -> bf16 cast (xh) if present.
__global__ __launch_bounds__(256) void prep(const int* __restrict__ ie, const float* __restrict__ im,
                                            const int* __restrict__ oe, const float* __restrict__ om,
                                            const float* __restrict__ x,
                                            unsigned short* __restrict__ Sb, unsigned short* __restrict__ xh) {
    int w = threadIdx.x >> 6, lane = threadIdx.x & 63;
    int n = blockIdx.x * 4 + w;
    int e = 0; float m = 0.f;
    if (lane < 16)      { e = ie[n * KK + lane];      m = im[n * KK + lane]; }
    else if (lane < 32) { e = oe[n * KK + lane - 16]; m = om[n * KK + lane - 16]; }
    float h = 0.f;
    #pragma unroll
    for (int j = 0; j < 32; ++j) {
        int ev = __shfl(e, j);
        float mv = __shfl(m, j);
        if (ev == lane) h += mv;
    }
    Sb[(size_t)n * 320 + 256 + lane] = f2bf(h);
    if (xh) {
        size_t base = (size_t)blockIdx.x * 1024 + threadIdx.x * 4;
        float4 v = ld4(x + base);
        ushort4 o; o.x = f2bf(v.x); o.y = f2bf(v.y); o.z = f2bf(v.z); o.w = f2bf(v.w);
        *reinterpret_cast<ushort4*>(xh + base) = o;
    }
}

// Pass-1 bf16 gather-aggregate: half-wave per neighbor parity, 16B/lane.
__global__ __launch_bounds__(256) void aggh(const unsigned short* __restrict__ src, const int* __restrict__ ii,
                                            const float* __restrict__ im, const int* __restrict__ oi,
                                            const float* __restrict__ om, unsigned short* __restrict__ Sb) {
    int w = threadIdx.x >> 6, lane = threadIdx.x & 63;
    int n = blockIdx.x * 4 + w;
    __shared__ int sidx[4][32];
    __shared__ float smsk[4][32];
    if (lane < 16) {
        sidx[w][lane] = ii[n * KK + lane]; sidx[w][lane + 16] = oi[n * KK + lane];
        smsk[w][lane] = im[n * KK + lane]; smsk[w][lane + 16] = om[n * KK + lane];
    }
    __syncthreads();
    int half = lane >> 5, c = (lane & 31) * 8;
    float acc[8] = {0.f, 0.f, 0.f, 0.f, 0.f, 0.f, 0.f, 0.f};
    #pragma unroll
    for (int j = 0; j < 16; ++j) {
        int j2 = j * 2 + half;
        int idx = sidx[w][j2];
        float m = smsk[w][j2];
        ushort8 u = *reinterpret_cast<const ushort8*>(src + (size_t)idx * DD + c);
        #pragma unroll
        for (int z = 0; z < 8; ++z) acc[z] += m * bf2f(u[z]);
    }
    #pragma unroll
    for (int z = 0; z < 8; ++z) acc[z] += __shfl_xor(acc[z], 32);
    if (half == 0) {
        unsigned short o8[8];
        #pragma unroll
        for (int z = 0; z < 8; ++z) o8[z] = f2bf(acc[z]);
        *reinterpret_cast<uint4*>(&Sb[(size_t)n * 320 + c]) = *reinterpret_cast<uint4*>(o8);
    }
}

// Pass-2 fp8 gather-aggregate: 4 row-groups x 16 lanes, 16B (16 elems)/lane, 8 loads total.
__global__ __launch_bounds__(256) void aggq(const unsigned char* __restrict__ src, const int* __restrict__ ii,
                                            const float* __restrict__ im, const int* __restrict__ oi,
                                            const float* __restrict__ om, unsigned short* __restrict__ Sb) {
    int w = threadIdx.x >> 6, lane = threadIdx.x & 63;
    int n = blockIdx.x * 4 + w;
    __shared__ int sidx[4][32];
    __shared__ float smsk[4][32];
    if (lane < 16) {
        sidx[w][lane] = ii[n * KK + lane]; sidx[w][lane + 16] = oi[n * KK + lane];
        smsk[w][lane] = im[n * KK + lane]; smsk[w][lane + 16] = om[n * KK + lane];
    }
    __syncthreads();
    int g = lane >> 4, cl = lane & 15;
    float acc[16];
    #pragma unroll
    for (int z = 0; z < 16; ++z) acc[z] = 0.f;
    #pragma unroll
    for (int j = 0; j < 8; ++j) {
        int r = g * 8 + j;
        int idx = sidx[w][r];
        float m = smsk[w][r];
        uint4 u = *reinterpret_cast<const uint4*>(src + (size_t)idx * DD + cl * 16);
        unsigned dw[4] = {u.x, u.y, u.z, u.w};
        #pragma unroll
        for (int d = 0; d < 4; ++d) {
            floatx2 f01 = __builtin_amdgcn_cvt_pk_f32_fp8(dw[d], false);
            floatx2 f23 = __builtin_amdgcn_cvt_pk_f32_fp8(dw[d], true);
            acc[d * 4 + 0] += m * f01.x; acc[d * 4 + 1] += m * f01.y;
            acc[d * 4 + 2] += m * f23.x; acc[d * 4 + 3] += m * f23.y;
        }
    }
    #pragma unroll
    for (int z = 0; z < 16; ++z) {
        acc[z] += __shfl_xor(acc[z], 16);
        acc[z] += __shfl_xor(acc[z], 32);
    }
    if (g == 0) {
        unsigned short o16[16];
        #pragma unroll
        for (int z = 0; z < 16; ++z) o16[z] = f2bf(acc[z]);
        uint4* dst = reinterpret_cast<uint4*>(&Sb[(size_t)n * 320 + cl * 16]);
        dst[0] = reinterpret_cast<uint4*>(o16)[0];
        dst[1] = reinterpret_cast<uint4*>(o16)[1];
    }
}

// f32-source fallback aggregate.
__global__ __launch_bounds__(256) void aggf(const float* __restrict__ src, const int* __restrict__ ii,
                                            const float* __restrict__ im, const int* __restrict__ oi,
                                            const float* __restrict__ om, unsigned short* __restrict__ Sb) {
    int w = threadIdx.x >> 6, lane = threadIdx.x & 63;
    int n = blockIdx.x * 4 + w;
    __shared__ int sidx[4][32];
    __shared__ float smsk[4][32];
    if (lane < 16) {
        sidx[w][lane] = ii[n * KK + lane]; sidx[w][lane + 16] = oi[n * KK + lane];
        smsk[w][lane] = im[n * KK + lane]; smsk[w][lane + 16] = om[n * KK + lane];
    }
    __syncthreads();
    int c = lane * 4;
    float4 s = make_float4(0.f, 0.f, 0.f, 0.f);
    #pragma unroll 4
    for (int j = 0; j < 32; ++j) {
        float4 xr = ld4(src + (size_t)sidx[w][j] * DD + c);
        float m = smsk[w][j];
        s.x += m * xr.x; s.y += m * xr.y; s.z += m * xr.z; s.w += m * xr.w;
    }
    ushort4 o; o.x = f2bf(s.x); o.y = f2bf(s.y); o.z = f2bf(s.z); o.w = f2bf(s.w);
    *reinterpret_cast<ushort4*>(&Sb[(size_t)n * 320 + c]) = o;
}

// hidden = x + 2*b1 + [S1|H] @ U1; writes f32 out + optional fp8 copy for the KLD path.
__global__ __launch_bounds__(256) void mm1(const unsigned short* __restrict__ Sb, const unsigned short* __restrict__ U,
                                           const float* __restrict__ x, const float* __restrict__ b,
                                           float* __restrict__ out, unsigned char* __restrict__ h8) {
    __shared__ unsigned short sA[16 * 336];
    int n0 = blockIdx.x * 16;
    for (int c = threadIdx.x; c < 640; c += 256) {
        int row = c / 40, k8 = c % 40;
        *reinterpret_cast<uint4*>(&sA[row * 336 + k8 * 8]) =
            *reinterpret_cast<const uint4*>(&Sb[(size_t)(n0 + row) * 320 + k8 * 8]);
    }
    __syncthreads();
    int lane = threadIdx.x & 63, w = threadIdx.x >> 6;
    int lr = lane & 15, quad = lane >> 4;
    float xp[4][4], bb[4];
    #pragma unroll
    for (int t = 0; t < 4; ++t) {
        int col = (w * 4 + t) * 16 + lr;
        bb[t] = 2.f * b[col];
        #pragma unroll
        for (int r = 0; r < 4; ++r)
            xp[t][r] = x[(size_t)(n0 + quad * 4 + r) * DD + col];
    }
    floatx4 z = {0.f, 0.f, 0.f, 0.f};
    floatx4 acc[4] = {z, z, z, z};
    for (int kt = 0; kt < 10; ++kt) {
        bf16x8 a = *reinterpret_cast<const bf16x8*>(&sA[lr * 336 + kt * 32 + quad * 8]);
        #pragma unroll
        for (int t = 0; t < 4; ++t) {
            bf16x8 bf = *reinterpret_cast<const bf16x8*>(&U[(size_t)((kt * NT1 + w * 4 + t) * 64 + lane) * 8]);
            acc[t] = __builtin_amdgcn_mfma_f32_16x16x32_bf16(a, bf, acc[t], 0, 0, 0);
        }
    }
    #pragma unroll
    for (int t = 0; t < 4; ++t) {
        int col = (w * 4 + t) * 16 + lr;
        #pragma unroll
        for (int r = 0; r < 4; ++r) {
            size_t o = (size_t)(n0 + quad * 4 + r) * DD + col;
            float v = xp[t][r] + bb[t] + acc[t][r];
            out[o] = v;
            if (h8) h8[o] = f2q(v);
        }
    }
}

// Fused gc2/gc3 matmul + fast tanh + separable KLD. blockIdx.y: 0 = mu, 1 = logvar.
__global__ __launch_bounds__(256) void mm23(const unsigned short* __restrict__ Sb, const unsigned short* __restrict__ U,
                                            const unsigned char* __restrict__ h8, const float* __restrict__ hf,
                                            const float* __restrict__ b2, const float* __restrict__ b3,
                                            float* __restrict__ partials) {
    __shared__ unsigned short sA[16 * 336];
    __shared__ float red[4];
    int n0 = blockIdx.x * 16, pass = blockIdx.y;
    for (int c = threadIdx.x; c < 640; c += 256) {
        int row = c / 40, k8 = c % 40;
        *reinterpret_cast<uint4*>(&sA[row * 336 + k8 * 8]) =
            *reinterpret_cast<const uint4*>(&Sb[(size_t)(n0 + row) * 320 + k8 * 8]);
    }
    __syncthreads();
    int lane = threadIdx.x & 63, w = threadIdx.x >> 6;
    int lr = lane & 15, quad = lane >> 4;
    const float* b = pass ? b3 : b2;
    float hp[4][4], bb[4];
    #pragma unroll
    for (int t = 0; t < 4; ++t) {
        int col = (w * 4 + t) * 16 + lr;
        bb[t] = 2.f * b[col];
        #pragma unroll
        for (int r = 0; r < 4; ++r) {
            size_t o = (size_t)(n0 + quad * 4 + r) * DD + col;
            hp[t][r] = h8 ? q2f(h8[o]) : hf[o];
        }
    }
    floatx4 z = {0.f, 0.f, 0.f, 0.f};
    floatx4 acc[4] = {z, z, z, z};
    for (int kt = 0; kt < 10; ++kt) {
        bf16x8 a = *reinterpret_cast<const bf16x8*>(&sA[lr * 336 + kt * 32 + quad * 8]);
        #pragma unroll
        for (int t = 0; t < 4; ++t) {
            int nt = pass * 16 + w * 4 + t;
            bf16x8 bf = *reinterpret_cast<const bf16x8*>(&U[(size_t)((kt * NT23 + nt) * 64 + lane) * 8]);
            acc[t] = __builtin_amdgcn_mfma_f32_16x16x32_bf16(a, bf, acc[t], 0, 0, 0);
        }
    }
    float kacc = 0.f;
    #pragma unroll
    for (int t = 0; t < 4; ++t) {
        #pragma unroll
        for (int r = 0; r < 4; ++r) {
            float v = hp[t][r] + bb[t] + acc[t][r];
            float e = __expf(2.f * v);
            float tt = 1.f - 2.f * __builtin_amdgcn_rcpf(e + 1.f);  // tanh(v)
            kacc += (pass == 0) ? (1.f - tt * tt) : (2.f * tt - __expf(2.f * tt));
        }
    }
    #pragma unroll
    for (int off = 32; off > 0; off >>= 1) kacc += __shfl_xor(kacc, off);
    if (lane == 0) red[w] = kacc;
    __syncthreads();
    if (threadIdx.x == 0)
        partials[pass * 1250 + blockIdx.x] = red[0] + red[1] + red[2] + red[3];
}

__global__ __launch_bounds__(256) void kred(const float* __restrict__ partials, int np,
                                            float* __restrict__ out) {
    __shared__ double red[256];
    double l = 0.0;
    for (int i = threadIdx.x; i < np; i += 256) l += (double)partials[i];
    red[threadIdx.x] = l;
    __syncthreads();
    for (int s = 128; s > 0; s >>= 1) {
        if (threadIdx.x < s) red[threadIdx.x] += red[threadIdx.x + s];
        __syncthreads();
    }
    if (threadIdx.x == 0)
        out[0] = (float)(red[0] * (-0.5 / ((double)NN * (double)NN)));
}

extern "C" void kernel_launch(void* const* d_in, const int* in_sizes, int n_in,
                              void* d_out, int out_size, void* d_ws, size_t ws_size,
                              hipStream_t stream) {
    const float* x  = (const float*)d_in[0];
    const int*   ii = (const int*)d_in[1];
    const int*   ie = (const int*)d_in[2];
    const float* im = (const float*)d_in[3];
    const int*   oi = (const int*)d_in[4];
    const int*   oe = (const int*)d_in[5];
    const float* om = (const float*)d_in[6];
    const float* e1 = (const float*)d_in[7];
    const float* W1 = (const float*)d_in[8];
    const float* b1 = (const float*)d_in[9];
    const float* e2 = (const float*)d_in[10];
    const float* W2 = (const float*)d_in[11];
    const float* b2 = (const float*)d_in[12];
    const float* e3 = (const float*)d_in[13];
    const float* W3 = (const float*)d_in[14];
    const float* b3 = (const float*)d_in[15];
    float* out = (float*)d_out;

    char* ws = (char*)d_ws;
    float*          EW    = (float*)(ws);                     // 3*64*256 f32   (196608 B)
    unsigned short* U1    = (unsigned short*)(ws + 196608);   // 163840 B
    unsigned short* U23   = (unsigned short*)(ws + 360448);   // 327680 B
    float*          parts = (float*)(ws + 688128);            // 2500 f32
    unsigned short* Sb    = (unsigned short*)(ws + 698128);   // 20000*320 bf16 (12.8 MB)
    unsigned short* xh    = (unsigned short*)(ws + 13498128); // 20000*256 bf16 (10.24 MB)
    unsigned char*  h8    = (unsigned char*)(ws + 23738128);  // 20000*256 fp8  (5.12 MB)
    int useBf = ws_size >= (size_t)28858128;

    ewk3  <<<dim3(VV, 3), 256, 0, stream>>>(e1, W1, e2, W2, e3, W3, EW);
    packU2<<<120, 256, 0, stream>>>(W1, EW, W2, EW + VV * DD, W3, EW + 2 * VV * DD, U1, U23);
    prep  <<<NN / 4, 256, 0, stream>>>(ie, im, oe, om, x, Sb, useBf ? xh : (unsigned short*)nullptr);
    if (useBf) {
        aggh<<<NN / 4, 256, 0, stream>>>(xh, ii, im, oi, om, Sb);
        mm1 <<<NN / 16, 256, 0, stream>>>(Sb, U1, x, b1, out, h8);
        aggq<<<NN / 4, 256, 0, stream>>>(h8, ii, im, oi, om, Sb);
        mm23<<<dim3(NN / 16, 2), 256, 0, stream>>>(Sb, U23, h8, (const float*)nullptr, b2, b3, parts);
    } else {
        aggf<<<NN / 4, 256, 0, stream>>>(x, ii, im, oi, om, Sb);
        mm1 <<<NN / 16, 256, 0, stream>>>(Sb, U1, x, b1, out, (unsigned char*)nullptr);
        aggf<<<NN / 4, 256, 0, stream>>>(out, ii, im, oi, om, Sb);
        mm23<<<dim3(NN / 16, 2), 256, 0, stream>>>(Sb, U23, (const unsigned char*)nullptr, out, b2, b3, parts);
    }
    kred<<<1, 256, 0, stream>>>(parts, 2500, out + (size_t)NN * DD);
}

// Round 5
// 223.764 us; speedup vs baseline: 2.0937x; 1.0310x over previous
//
#include <hip/hip_runtime.h>
#include <math.h>

#define NN 20000
#define KK 16
#define DD 256
#define VV 64
#define NT1 16

typedef __attribute__((ext_vector_type(8))) __bf16 bf16x8;
typedef __attribute__((ext_vector_type(4))) float floatx4;
typedef __attribute__((ext_vector_type(2))) float floatx2;
typedef __attribute__((ext_vector_type(8))) unsigned short ushort8;

__device__ __forceinline__ float4 ld4(const float* p) { return *reinterpret_cast<const float4*>(p); }

__device__ __forceinline__ unsigned short f2bf(float f) {
    union { float f; unsigned u; } v; v.f = f;
    unsigned r = v.u + 0x7FFFu + ((v.u >> 16) & 1u);
    return (unsigned short)(r >> 16);
}
__device__ __forceinline__ float bf2f(unsigned short u) {
    union { unsigned u; float f; } v; v.u = ((unsigned)u) << 16;
    return v.f;
}
__device__ __forceinline__ unsigned char f2q(float f) {  // fp8 e4m3, RTNE
    return (unsigned char)(__builtin_amdgcn_cvt_pk_fp8_f32(f, 0.f, 0u, false) & 0xFFu);
}
__device__ __forceinline__ float q2f(unsigned char q) {
    floatx2 r = __builtin_amdgcn_cvt_pk_f32_fp8((unsigned)q, false);
    return r.x;
}
__device__ __forceinline__ float ftanh(float v) {
    float e = __expf(2.f * v);
    return 1.f - 2.f * __builtin_amdgcn_rcpf(e + 1.f);
}

// EW[layer][v][d] = sum_j emb_l[v][j] * W_l[256+j][d]
__global__ __launch_bounds__(256) void ewk3(const float* __restrict__ e1, const float* __restrict__ W1,
                                            const float* __restrict__ e2, const float* __restrict__ W2,
                                            const float* __restrict__ e3, const float* __restrict__ W3,
                                            float* __restrict__ EW) {
    int layer = blockIdx.y;
    const float* emb = layer == 0 ? e1 : (layer == 1 ? e2 : e3);
    const float* W   = layer == 0 ? W1 : (layer == 1 ? W2 : W3);
    int v = blockIdx.x, d = threadIdx.x;
    float acc = 0.f;
    #pragma unroll 8
    for (int j = 0; j < 256; ++j)
        acc += emb[v * DD + j] * W[(size_t)(256 + j) * DD + d];
    EW[(size_t)layer * VV * DD + v * DD + d] = acc;
}

// Pack B = [W_top(256); EW(64)] (K=320) into MFMA B-fragment layout; U1 (16 ntiles) and U23 (32).
__global__ __launch_bounds__(256) void packU2(const float* __restrict__ W1, const float* __restrict__ EW1,
                                              const float* __restrict__ W2, const float* __restrict__ EW2,
                                              const float* __restrict__ W3, const float* __restrict__ EW3,
                                              unsigned short* __restrict__ U1, unsigned short* __restrict__ U23) {
    int blk = blockIdx.x;
    int NT; unsigned short* U; const float *Wa, *EWa, *Wb, *EWb; int g;
    if (blk < 40) { NT = 16; U = U1;  Wa = W1; EWa = EW1; Wb = W1; EWb = EW1; g = blk * 256 + threadIdx.x; }
    else          { NT = 32; U = U23; Wa = W2; EWa = EW2; Wb = W3; EWb = EW3; g = (blk - 40) * 256 + threadIdx.x; }
    int lane = g & 63, ntk = g >> 6;
    int nt = ntk % NT, kt = ntk / NT;
    if (kt >= 10) return;
    int n = nt * 16 + (lane & 15);
    int kbase = kt * 32 + (lane >> 4) * 8;
    const float* W = Wa; const float* EW = EWa;
    if (n >= 256) { W = Wb; EW = EWb; n -= 256; }
    unsigned short o8[8];
    #pragma unroll
    for (int j = 0; j < 8; ++j) {
        int k = kbase + j;
        float v = (k < 256) ? W[(size_t)k * DD + n] : EW[(size_t)(k - 256) * DD + n];
        o8[j] = f2bf(v);
    }
    *reinterpret_cast<uint4*>(&U[(size_t)g * 8]) = *reinterpret_cast<uint4*>(o8);
}

// Masked edge histogram -> compact Hc[n][64] bf16; plus x -> bf16 cast (xh).
__global__ __launch_bounds__(256) void prep(const int* __restrict__ ie, const float* __restrict__ im,
                                            const int* __restrict__ oe, const float* __restrict__ om,
                                            const float* __restrict__ x,
                                            unsigned short* __restrict__ Hc, unsigned short* __restrict__ xh) {
    int w = threadIdx.x >> 6, lane = threadIdx.x & 63;
    int n = blockIdx.x * 4 + w;
    int e = 0; float m = 0.f;
    if (lane < 16)      { e = ie[n * KK + lane];      m = im[n * KK + lane]; }
    else if (lane < 32) { e = oe[n * KK + lane - 16]; m = om[n * KK + lane - 16]; }
    float h = 0.f;
    #pragma unroll
    for (int j = 0; j < 32; ++j) {
        int ev = __shfl(e, j);
        float mv = __shfl(m, j);
        if (ev == lane) h += mv;
    }
    Hc[(size_t)n * 64 + lane] = f2bf(h);
    size_t base = (size_t)blockIdx.x * 1024 + threadIdx.x * 4;
    float4 v = ld4(x + base);
    ushort4 o; o.x = f2bf(v.x); o.y = f2bf(v.y); o.z = f2bf(v.z); o.w = f2bf(v.w);
    *reinterpret_cast<ushort4*>(xh + base) = o;
}

// Fused pass 1: bf16 gather-aggregate of x straight into LDS A-tile, then
// hidden = x + 2*b1 + [S1|H] @ U1.  Writes f32 out + fp8 copy for the KLD path.
__global__ __launch_bounds__(256) void fmm1(const unsigned short* __restrict__ xh, const unsigned short* __restrict__ Hc,
                                            const int* __restrict__ ii, const float* __restrict__ im,
                                            const int* __restrict__ oi, const float* __restrict__ om,
                                            const unsigned short* __restrict__ U, const float* __restrict__ b,
                                            float* __restrict__ out, unsigned char* __restrict__ h8) {
    __shared__ unsigned short sA[16 * 336];
    __shared__ int sidx[16][32];
    __shared__ float smsk[16][32];
    int n0 = blockIdx.x * 16;
    int tid = threadIdx.x;
    for (int q = tid; q < 512; q += 256) {
        int r = q >> 5, j = q & 31;
        int n = n0 + r;
        sidx[r][j] = (j < 16) ? ii[n * KK + j] : oi[n * KK + j - 16];
        smsk[r][j] = (j < 16) ? im[n * KK + j] : om[n * KK + j - 16];
    }
    if (tid < 128) {  // stage H cols [256,320)
        int r = tid >> 3, k8 = tid & 7;
        *reinterpret_cast<uint4*>(&sA[r * 336 + 256 + k8 * 8]) =
            *reinterpret_cast<const uint4*>(&Hc[(size_t)(n0 + r) * 64 + k8 * 8]);
    }
    __syncthreads();
    int lane = tid & 63, w = tid >> 6;
    int half = lane >> 5, c = (lane & 31) * 8;
    #pragma unroll
    for (int rr = 0; rr < 4; ++rr) {
        int row = w * 4 + rr;
        float acc[8] = {0.f, 0.f, 0.f, 0.f, 0.f, 0.f, 0.f, 0.f};
        #pragma unroll
        for (int j = 0; j < 16; ++j) {
            int j2 = j * 2 + half;
            int idx = sidx[row][j2];
            float m = smsk[row][j2];
            ushort8 u = *reinterpret_cast<const ushort8*>(xh + (size_t)idx * DD + c);
            #pragma unroll
            for (int z = 0; z < 8; ++z) acc[z] += m * bf2f(u[z]);
        }
        #pragma unroll
        for (int z = 0; z < 8; ++z) acc[z] += __shfl_xor(acc[z], 32);
        if (half == 0) {
            unsigned short o8[8];
            #pragma unroll
            for (int z = 0; z < 8; ++z) o8[z] = f2bf(acc[z]);
            *reinterpret_cast<uint4*>(&sA[row * 336 + c]) = *reinterpret_cast<uint4*>(o8);
        }
    }
    __syncthreads();
    int lr = lane & 15, quad = lane >> 4;
    float xp[4][4], bb[4];
    #pragma unroll
    for (int t = 0; t < 4; ++t) {
        int col = (w * 4 + t) * 16 + lr;
        bb[t] = 2.f * b[col];
        #pragma unroll
        for (int r = 0; r < 4; ++r)
            xp[t][r] = bf2f(xh[(size_t)(n0 + quad * 4 + r) * DD + col]);
    }
    floatx4 z = {0.f, 0.f, 0.f, 0.f};
    floatx4 acc[4] = {z, z, z, z};
    for (int kt = 0; kt < 10; ++kt) {
        bf16x8 a = *reinterpret_cast<const bf16x8*>(&sA[lr * 336 + kt * 32 + quad * 8]);
        #pragma unroll
        for (int t = 0; t < 4; ++t) {
            bf16x8 bf = *reinterpret_cast<const bf16x8*>(&U[(size_t)((kt * NT1 + w * 4 + t) * 64 + lane) * 8]);
            acc[t] = __builtin_amdgcn_mfma_f32_16x16x32_bf16(a, bf, acc[t], 0, 0, 0);
        }
    }
    #pragma unroll
    for (int t = 0; t < 4; ++t) {
        int col = (w * 4 + t) * 16 + lr;
        #pragma unroll
        for (int r = 0; r < 4; ++r) {
            size_t o = (size_t)(n0 + quad * 4 + r) * DD + col;
            float v = xp[t][r] + bb[t] + acc[t][r];
            out[o] = v;
            h8[o] = f2q(v);
        }
    }
}

// Fused pass 2: fp8 gather-aggregate of hidden into LDS A-tile, then BOTH mu and
// logvar matmuls in one block + fast tanh + separable KLD partial.
__global__ __launch_bounds__(256) void fmm23(const unsigned char* __restrict__ h8, const unsigned short* __restrict__ Hc,
                                             const int* __restrict__ ii, const float* __restrict__ im,
                                             const int* __restrict__ oi, const float* __restrict__ om,
                                             const unsigned short* __restrict__ U, const float* __restrict__ b2,
                                             const float* __restrict__ b3, float* __restrict__ partials) {
    __shared__ unsigned short sA[16 * 336];
    __shared__ int sidx[16][32];
    __shared__ float smsk[16][32];
    __shared__ float red[4];
    int n0 = blockIdx.x * 16;
    int tid = threadIdx.x;
    for (int q = tid; q < 512; q += 256) {
        int r = q >> 5, j = q & 31;
        int n = n0 + r;
        sidx[r][j] = (j < 16) ? ii[n * KK + j] : oi[n * KK + j - 16];
        smsk[r][j] = (j < 16) ? im[n * KK + j] : om[n * KK + j - 16];
    }
    if (tid < 128) {
        int r = tid >> 3, k8 = tid & 7;
        *reinterpret_cast<uint4*>(&sA[r * 336 + 256 + k8 * 8]) =
            *reinterpret_cast<const uint4*>(&Hc[(size_t)(n0 + r) * 64 + k8 * 8]);
    }
    __syncthreads();
    int lane = tid & 63, w = tid >> 6;
    int g = lane >> 4, cl = lane & 15;
    #pragma unroll
    for (int rr = 0; rr < 4; ++rr) {
        int row = w * 4 + rr;
        float acc[16];
        #pragma unroll
        for (int z = 0; z < 16; ++z) acc[z] = 0.f;
        #pragma unroll
        for (int j = 0; j < 8; ++j) {
            int r = g * 8 + j;
            int idx = sidx[row][r];
            float m = smsk[row][r];
            uint4 u = *reinterpret_cast<const uint4*>(h8 + (size_t)idx * DD + cl * 16);
            unsigned dw[4] = {u.x, u.y, u.z, u.w};
            #pragma unroll
            for (int d = 0; d < 4; ++d) {
                floatx2 f01 = __builtin_amdgcn_cvt_pk_f32_fp8(dw[d], false);
                floatx2 f23 = __builtin_amdgcn_cvt_pk_f32_fp8(dw[d], true);
                acc[d * 4 + 0] += m * f01.x; acc[d * 4 + 1] += m * f01.y;
                acc[d * 4 + 2] += m * f23.x; acc[d * 4 + 3] += m * f23.y;
            }
        }
        #pragma unroll
        for (int z = 0; z < 16; ++z) {
            acc[z] += __shfl_xor(acc[z], 16);
            acc[z] += __shfl_xor(acc[z], 32);
        }
        if (g == 0) {
            unsigned short o16[16];
            #pragma unroll
            for (int z = 0; z < 16; ++z) o16[z] = f2bf(acc[z]);
            uint4* dst = reinterpret_cast<uint4*>(&sA[row * 336 + cl * 16]);
            dst[0] = reinterpret_cast<uint4*>(o16)[0];
            dst[1] = reinterpret_cast<uint4*>(o16)[1];
        }
    }
    __syncthreads();
    int lr = lane & 15, quad = lane >> 4;
    float hp[4][4], bm[4], bl[4];
    #pragma unroll
    for (int t = 0; t < 4; ++t) {
        int col = (w * 4 + t) * 16 + lr;
        bm[t] = 2.f * b2[col];
        bl[t] = 2.f * b3[col];
        #pragma unroll
        for (int r = 0; r < 4; ++r)
            hp[t][r] = q2f(h8[(size_t)(n0 + quad * 4 + r) * DD + col]);
    }
    floatx4 z = {0.f, 0.f, 0.f, 0.f};
    floatx4 am[4] = {z, z, z, z};
    floatx4 al[4] = {z, z, z, z};
    for (int kt = 0; kt < 10; ++kt) {
        bf16x8 a = *reinterpret_cast<const bf16x8*>(&sA[lr * 336 + kt * 32 + quad * 8]);
        #pragma unroll
        for (int t = 0; t < 4; ++t) {
            int nt = w * 4 + t;
            bf16x8 bmu = *reinterpret_cast<const bf16x8*>(&U[(size_t)((kt * 32 + nt) * 64 + lane) * 8]);
            bf16x8 blv = *reinterpret_cast<const bf16x8*>(&U[(size_t)((kt * 32 + 16 + nt) * 64 + lane) * 8]);
            am[t] = __builtin_amdgcn_mfma_f32_16x16x32_bf16(a, bmu, am[t], 0, 0, 0);
            al[t] = __builtin_amdgcn_mfma_f32_16x16x32_bf16(a, blv, al[t], 0, 0, 0);
        }
    }
    float kacc = 0.f;
    #pragma unroll
    for (int t = 0; t < 4; ++t) {
        #pragma unroll
        for (int r = 0; r < 4; ++r) {
            float h = hp[t][r];
            float tm = ftanh(h + bm[t] + am[t][r]);
            float tl = ftanh(h + bl[t] + al[t][r]);
            kacc += (1.f - tm * tm) + (2.f * tl - __expf(2.f * tl));
        }
    }
    #pragma unroll
    for (int off = 32; off > 0; off >>= 1) kacc += __shfl_xor(kacc, off);
    if (lane == 0) red[w] = kacc;
    __syncthreads();
    if (tid == 0)
        partials[blockIdx.x] = red[0] + red[1] + red[2] + red[3];
}

__global__ __launch_bounds__(256) void kred(const float* __restrict__ partials, int np,
                                            float* __restrict__ out) {
    __shared__ double red[256];
    double l = 0.0;
    for (int i = threadIdx.x; i < np; i += 256) l += (double)partials[i];
    red[threadIdx.x] = l;
    __syncthreads();
    for (int s = 128; s > 0; s >>= 1) {
        if (threadIdx.x < s) red[threadIdx.x] += red[threadIdx.x + s];
        __syncthreads();
    }
    if (threadIdx.x == 0)
        out[0] = (float)(red[0] * (-0.5 / ((double)NN * (double)NN)));
}

extern "C" void kernel_launch(void* const* d_in, const int* in_sizes, int n_in,
                              void* d_out, int out_size, void* d_ws, size_t ws_size,
                              hipStream_t stream) {
    const float* x  = (const float*)d_in[0];
    const int*   ii = (const int*)d_in[1];
    const int*   ie = (const int*)d_in[2];
    const float* im = (const float*)d_in[3];
    const int*   oi = (const int*)d_in[4];
    const int*   oe = (const int*)d_in[5];
    const float* om = (const float*)d_in[6];
    const float* e1 = (const float*)d_in[7];
    const float* W1 = (const float*)d_in[8];
    const float* b1 = (const float*)d_in[9];
    const float* e2 = (const float*)d_in[10];
    const float* W2 = (const float*)d_in[11];
    const float* b2 = (const float*)d_in[12];
    const float* e3 = (const float*)d_in[13];
    const float* W3 = (const float*)d_in[14];
    const float* b3 = (const float*)d_in[15];
    float* out = (float*)d_out;

    char* ws = (char*)d_ws;                                   // ws_size ~268 MB; we use ~18.6 MB
    float*          EW    = (float*)(ws);                     // 3*64*256 f32   (196608 B)
    unsigned short* U1    = (unsigned short*)(ws + 196608);   // 163840 B
    unsigned short* U23   = (unsigned short*)(ws + 360448);   // 327680 B
    float*          parts = (float*)(ws + 688128);            // 1250 f32 (pad to 8000 B)
    unsigned short* Hc    = (unsigned short*)(ws + 696128);   // 20000*64 bf16  (2.56 MB)
    unsigned short* xh    = (unsigned short*)(ws + 3256128);  // 20000*256 bf16 (10.24 MB)
    unsigned char*  h8    = (unsigned char*)(ws + 13496128);  // 20000*256 fp8  (5.12 MB)

    ewk3  <<<dim3(VV, 3), 256, 0, stream>>>(e1, W1, e2, W2, e3, W3, EW);
    packU2<<<120, 256, 0, stream>>>(W1, EW, W2, EW + VV * DD, W3, EW + 2 * VV * DD, U1, U23);
    prep  <<<NN / 4, 256, 0, stream>>>(ie, im, oe, om, x, Hc, xh);
    fmm1  <<<NN / 16, 256, 0, stream>>>(xh, Hc, ii, im, oi, om, U1, b1, out, h8);
    fmm23 <<<NN / 16, 256, 0, stream>>>(h8, Hc, ii, im, oi, om, U23, b2, b3, parts);
    kred  <<<1, 256, 0, stream>>>(parts, NN / 16, out + (size_t)NN * DD);
}